// Round 3
// baseline (647.633 us; speedup 1.0000x reference)
//
#include <hip/hip_runtime.h>

// DiffeomorphicTransform2: scaling-and-squaring integration.
// flow: [1, 3, 160, 192, 160] fp32.  f = flow/2^7; 7x: f += trilinear(f, grid+disp(f)).
// disp mapping: x<-ch2, y<-ch1, z<-ch0. Border clamp, align_corners=True.
//
// R2 -> R3:
//  * Dedicated pack pass (streaming, ~25us) replaces the slow planar-gather
//    step 1 (115us); all 7 sampling steps now run the packed fast path.
//  * float4-padded voxels (16B aligned) when ws_size fits 2x78.6MB: kills the
//    19% line-straddle penalty of unaligned 12B dwordx3 gathers. Runtime
//    fallback to float3 layout (out+ws ping-pong) if ws is small.
//  * All math fp32, identical expression order to R2 (absmax budget is tiny).

#define DD 160
#define HH 192
#define WW 160
#define NVOX (DD * HH * WW)     // 4,915,200
#define NBLK (NVOX / 256)       // 19200

__device__ __forceinline__ int swizzled_tid() {
    // XCD-aware: physical block b lands on XCD b%8; give XCD k a contiguous slab.
    const int b = blockIdx.x;
    const int l = (b & 7) * (NBLK / 8) + (b >> 3);
    return l * 256 + (int)threadIdx.x;
}

// ---------- pack kernels: planar fp32 -> packed (x scale) ----------
__global__ __launch_bounds__(256) void pack4_kernel(const float* __restrict__ in,
                                                    float4* __restrict__ out, float scale) {
    const int tid = blockIdx.x * 256 + (int)threadIdx.x;
    float4 v;
    v.x = in[tid] * scale;
    v.y = in[NVOX + tid] * scale;
    v.z = in[2 * NVOX + tid] * scale;
    v.w = 0.0f;
    out[tid] = v;
}

__global__ __launch_bounds__(256) void pack3_kernel(const float* __restrict__ in,
                                                    float* __restrict__ out, float scale) {
    const int tid = blockIdx.x * 256 + (int)threadIdx.x;
    float* q = out + 3 * tid;
    q[0] = in[tid] * scale;
    q[1] = in[NVOX + tid] * scale;
    q[2] = in[2 * NVOX + tid] * scale;
}

// ---------- shared per-voxel geometry ----------
struct Corners {
    int i000, i001, i010, i011, i100, i101, i110, i111;
    float w000, w001, w010, w011, w100, w101, w110, w111;
};

__device__ __forceinline__ Corners make_corners(int tid, float f0, float f1, float f2) {
    const int w = tid % WW;
    const int t = tid / WW;
    const int h = t % HH;
    const int d = t / HH;

    const float gx = -1.0f + 2.0f * (float)w / (float)(WW - 1);
    const float gy = -1.0f + 2.0f * (float)h / (float)(HH - 1);
    const float gz = -1.0f + 2.0f * (float)d / (float)(DD - 1);
    float x = (gx + f2 + 1.0f) * (0.5f * (float)(WW - 1));
    float y = (gy + f1 + 1.0f) * (0.5f * (float)(HH - 1));
    float z = (gz + f0 + 1.0f) * (0.5f * (float)(DD - 1));
    x = fminf(fmaxf(x, 0.0f), (float)(WW - 1));
    y = fminf(fmaxf(y, 0.0f), (float)(HH - 1));
    z = fminf(fmaxf(z, 0.0f), (float)(DD - 1));

    const float x0f = floorf(x), y0f = floorf(y), z0f = floorf(z);
    const float wx = x - x0f, wy = y - y0f, wz = z - z0f;
    const int x0 = (int)x0f, y0 = (int)y0f, z0 = (int)z0f;
    const int x1 = min(x0 + 1, WW - 1);
    const int y1 = min(y0 + 1, HH - 1);
    const int z1 = min(z0 + 1, DD - 1);

    const int b00 = (z0 * HH + y0) * WW;
    const int b01 = (z0 * HH + y1) * WW;
    const int b10 = (z1 * HH + y0) * WW;
    const int b11 = (z1 * HH + y1) * WW;

    Corners c;
    c.i000 = b00 + x0; c.i001 = b00 + x1;
    c.i010 = b01 + x0; c.i011 = b01 + x1;
    c.i100 = b10 + x0; c.i101 = b10 + x1;
    c.i110 = b11 + x0; c.i111 = b11 + x1;

    const float omx = 1.0f - wx, omy = 1.0f - wy, omz = 1.0f - wz;
    c.w000 = omz * omy * omx; c.w001 = omz * omy * wx;
    c.w010 = omz * wy * omx;  c.w011 = omz * wy * wx;
    c.w100 = wz * omy * omx;  c.w101 = wz * omy * wx;
    c.w110 = wz * wy * omx;   c.w111 = wz * wy * wx;
    return c;
}

// ---------- float4-layout step ----------
template<bool OUT_PLANAR>
__global__ __launch_bounds__(256) void step4_kernel(const float4* __restrict__ in,
                                                    float* __restrict__ out) {
    const int tid = swizzled_tid();
    const float4 f = in[tid];
    const Corners c = make_corners(tid, f.x, f.y, f.z);

    const float4 q000 = in[c.i000], q001 = in[c.i001];
    const float4 q010 = in[c.i010], q011 = in[c.i011];
    const float4 q100 = in[c.i100], q101 = in[c.i101];
    const float4 q110 = in[c.i110], q111 = in[c.i111];

    const float s0 = q000.x*c.w000 + q001.x*c.w001 + q010.x*c.w010 + q011.x*c.w011
                   + q100.x*c.w100 + q101.x*c.w101 + q110.x*c.w110 + q111.x*c.w111;
    const float s1 = q000.y*c.w000 + q001.y*c.w001 + q010.y*c.w010 + q011.y*c.w011
                   + q100.y*c.w100 + q101.y*c.w101 + q110.y*c.w110 + q111.y*c.w111;
    const float s2 = q000.z*c.w000 + q001.z*c.w001 + q010.z*c.w010 + q011.z*c.w011
                   + q100.z*c.w100 + q101.z*c.w101 + q110.z*c.w110 + q111.z*c.w111;

    const float r0 = f.x + s0, r1 = f.y + s1, r2 = f.z + s2;
    if (OUT_PLANAR) {
        out[tid]            = r0;
        out[NVOX + tid]     = r1;
        out[2 * NVOX + tid] = r2;
    } else {
        float4 v; v.x = r0; v.y = r1; v.z = r2; v.w = 0.0f;
        ((float4*)out)[tid] = v;
    }
}

// ---------- float3-layout step (fallback, fits in out+ws) ----------
template<bool OUT_PLANAR>
__global__ __launch_bounds__(256) void step3_kernel(const float* __restrict__ in,
                                                    float* __restrict__ out) {
    const int tid = swizzled_tid();
    const float* p = in + 3 * tid;
    const float f0 = p[0], f1 = p[1], f2 = p[2];
    const Corners c = make_corners(tid, f0, f1, f2);

    const float* p000 = in + 3 * c.i000;  const float* p001 = in + 3 * c.i001;
    const float* p010 = in + 3 * c.i010;  const float* p011 = in + 3 * c.i011;
    const float* p100 = in + 3 * c.i100;  const float* p101 = in + 3 * c.i101;
    const float* p110 = in + 3 * c.i110;  const float* p111 = in + 3 * c.i111;
    const float a0 = p000[0], a1 = p000[1], a2 = p000[2];
    const float b0 = p001[0], b1 = p001[1], b2 = p001[2];
    const float c0 = p010[0], c1 = p010[1], c2 = p010[2];
    const float e0 = p011[0], e1 = p011[1], e2 = p011[2];
    const float g0 = p100[0], g1 = p100[1], g2 = p100[2];
    const float h0 = p101[0], h1 = p101[1], h2 = p101[2];
    const float j0 = p110[0], j1 = p110[1], j2 = p110[2];
    const float k0 = p111[0], k1 = p111[1], k2 = p111[2];

    const float s0 = a0*c.w000 + b0*c.w001 + c0*c.w010 + e0*c.w011
                   + g0*c.w100 + h0*c.w101 + j0*c.w110 + k0*c.w111;
    const float s1 = a1*c.w000 + b1*c.w001 + c1*c.w010 + e1*c.w011
                   + g1*c.w100 + h1*c.w101 + j1*c.w110 + k1*c.w111;
    const float s2 = a2*c.w000 + b2*c.w001 + c2*c.w010 + e2*c.w011
                   + g2*c.w100 + h2*c.w101 + j2*c.w110 + k2*c.w111;

    const float r0 = f0 + s0, r1 = f1 + s1, r2 = f2 + s2;
    if (OUT_PLANAR) {
        out[tid]            = r0;
        out[NVOX + tid]     = r1;
        out[2 * NVOX + tid] = r2;
    } else {
        float* q = out + 3 * tid;
        q[0] = r0; q[1] = r1; q[2] = r2;
    }
}

extern "C" void kernel_launch(void* const* d_in, const int* in_sizes, int n_in,
                              void* d_out, int out_size, void* d_ws, size_t ws_size,
                              hipStream_t stream) {
    const float* flow = (const float*)d_in[0];
    float* out = (float*)d_out;
    const float inv128 = 1.0f / 128.0f;   // 1 / 2^TIME_STEP (exact)

    const size_t need4 = 2ull * NVOX * sizeof(float4);   // 157.3 MB
    if (ws_size >= need4) {
        // Path A: two float4-padded buffers, both in ws.
        float4* A = (float4*)d_ws;
        float4* B = A + NVOX;
        pack4_kernel<<<NBLK, 256, 0, stream>>>(flow, A, inv128);
        step4_kernel<false><<<NBLK, 256, 0, stream>>>(A, (float*)B);  // s1
        step4_kernel<false><<<NBLK, 256, 0, stream>>>(B, (float*)A);  // s2
        step4_kernel<false><<<NBLK, 256, 0, stream>>>(A, (float*)B);  // s3
        step4_kernel<false><<<NBLK, 256, 0, stream>>>(B, (float*)A);  // s4
        step4_kernel<false><<<NBLK, 256, 0, stream>>>(A, (float*)B);  // s5
        step4_kernel<false><<<NBLK, 256, 0, stream>>>(B, (float*)A);  // s6
        step4_kernel<true ><<<NBLK, 256, 0, stream>>>(A, out);        // s7 -> planar
    } else {
        // Path B: float3-packed ping-pong between ws and out.
        float* ws = (float*)d_ws;
        pack3_kernel<<<NBLK, 256, 0, stream>>>(flow, ws, inv128);
        step3_kernel<false><<<NBLK, 256, 0, stream>>>(ws, out);   // s1
        step3_kernel<false><<<NBLK, 256, 0, stream>>>(out, ws);   // s2
        step3_kernel<false><<<NBLK, 256, 0, stream>>>(ws, out);   // s3
        step3_kernel<false><<<NBLK, 256, 0, stream>>>(out, ws);   // s4
        step3_kernel<false><<<NBLK, 256, 0, stream>>>(ws, out);   // s5
        step3_kernel<false><<<NBLK, 256, 0, stream>>>(out, ws);   // s6
        step3_kernel<true ><<<NBLK, 256, 0, stream>>>(ws, out);   // s7 -> planar
    }
}

// Round 4
// 566.727 us; speedup vs baseline: 1.1428x; 1.1428x over previous
//
#include <hip/hip_runtime.h>

// DiffeomorphicTransform2: scaling-and-squaring integration.
// flow: [1, 3, 160, 192, 160] fp32.  f = flow/2^7; 7x: f += trilinear(f, grid+disp(f)).
// disp mapping: x<-ch2, y<-ch1, z<-ch0. Border clamp, align_corners=True.
//
// R3 -> R4:
//  * REVERT float4 layout (R3 regressed: 93 MB fetch/step vs 34 MB, 94.6 us/step).
//    Random late-step gathers cost ~lines-per-corner-cluster; float3 (12B) shares
//    lines between x0/x1 corners better (4.5 lines/voxel vs 5) and has a 25%
//    smaller footprint (59 MB vs 78.6 MB) -> better L2/L3 behavior.
//  * KEEP the pack pass (the real R3 win): streaming ~20 us replaces the 115 us
//    planar-gather step 1; all 7 sampling steps run the packed fast path.
//    Scale 2^-7 is a pure exponent shift -> pre-scaling is bit-identical.
//  * Ping-pong two float3 buffers inside ws; step 7 writes planar to d_out.

#define DD 160
#define HH 192
#define WW 160
#define NVOX (DD * HH * WW)     // 4,915,200
#define NBLK (NVOX / 256)       // 19200

__device__ __forceinline__ int swizzled_tid() {
    // XCD-aware: physical block b lands on XCD b%8; give XCD k a contiguous slab.
    const int b = blockIdx.x;
    const int l = (b & 7) * (NBLK / 8) + (b >> 3);
    return l * 256 + (int)threadIdx.x;
}

// ---------- pack: planar fp32 -> packed float3 (x scale), streaming ----------
__global__ __launch_bounds__(256) void pack3_kernel(const float* __restrict__ in,
                                                    float* __restrict__ out, float scale) {
    const int tid = blockIdx.x * 256 + (int)threadIdx.x;
    float* q = out + 3 * tid;
    q[0] = in[tid] * scale;
    q[1] = in[NVOX + tid] * scale;
    q[2] = in[2 * NVOX + tid] * scale;
}

// ---------- per-voxel geometry ----------
struct Corners {
    int i000, i001, i010, i011, i100, i101, i110, i111;
    float w000, w001, w010, w011, w100, w101, w110, w111;
};

__device__ __forceinline__ Corners make_corners(int tid, float f0, float f1, float f2) {
    const int w = tid % WW;
    const int t = tid / WW;
    const int h = t % HH;
    const int d = t / HH;

    const float gx = -1.0f + 2.0f * (float)w / (float)(WW - 1);
    const float gy = -1.0f + 2.0f * (float)h / (float)(HH - 1);
    const float gz = -1.0f + 2.0f * (float)d / (float)(DD - 1);
    float x = (gx + f2 + 1.0f) * (0.5f * (float)(WW - 1));
    float y = (gy + f1 + 1.0f) * (0.5f * (float)(HH - 1));
    float z = (gz + f0 + 1.0f) * (0.5f * (float)(DD - 1));
    x = fminf(fmaxf(x, 0.0f), (float)(WW - 1));
    y = fminf(fmaxf(y, 0.0f), (float)(HH - 1));
    z = fminf(fmaxf(z, 0.0f), (float)(DD - 1));

    const float x0f = floorf(x), y0f = floorf(y), z0f = floorf(z);
    const float wx = x - x0f, wy = y - y0f, wz = z - z0f;
    const int x0 = (int)x0f, y0 = (int)y0f, z0 = (int)z0f;
    const int x1 = min(x0 + 1, WW - 1);
    const int y1 = min(y0 + 1, HH - 1);
    const int z1 = min(z0 + 1, DD - 1);

    const int b00 = (z0 * HH + y0) * WW;
    const int b01 = (z0 * HH + y1) * WW;
    const int b10 = (z1 * HH + y0) * WW;
    const int b11 = (z1 * HH + y1) * WW;

    Corners c;
    c.i000 = b00 + x0; c.i001 = b00 + x1;
    c.i010 = b01 + x0; c.i011 = b01 + x1;
    c.i100 = b10 + x0; c.i101 = b10 + x1;
    c.i110 = b11 + x0; c.i111 = b11 + x1;

    const float omx = 1.0f - wx, omy = 1.0f - wy, omz = 1.0f - wz;
    c.w000 = omz * omy * omx; c.w001 = omz * omy * wx;
    c.w010 = omz * wy * omx;  c.w011 = omz * wy * wx;
    c.w100 = wz * omy * omx;  c.w101 = wz * omy * wx;
    c.w110 = wz * wy * omx;   c.w111 = wz * wy * wx;
    return c;
}

// ---------- float3-layout step ----------
template<bool OUT_PLANAR>
__global__ __launch_bounds__(256) void step3_kernel(const float* __restrict__ in,
                                                    float* __restrict__ out) {
    const int tid = swizzled_tid();
    const float* p = in + 3 * tid;
    const float f0 = p[0], f1 = p[1], f2 = p[2];
    const Corners c = make_corners(tid, f0, f1, f2);

    // 8 gathers of 12 contiguous bytes (dwordx3), issued up front for MLP
    const float* p000 = in + 3 * c.i000;  const float* p001 = in + 3 * c.i001;
    const float* p010 = in + 3 * c.i010;  const float* p011 = in + 3 * c.i011;
    const float* p100 = in + 3 * c.i100;  const float* p101 = in + 3 * c.i101;
    const float* p110 = in + 3 * c.i110;  const float* p111 = in + 3 * c.i111;
    const float a0 = p000[0], a1 = p000[1], a2 = p000[2];
    const float b0 = p001[0], b1 = p001[1], b2 = p001[2];
    const float c0 = p010[0], c1 = p010[1], c2 = p010[2];
    const float e0 = p011[0], e1 = p011[1], e2 = p011[2];
    const float g0 = p100[0], g1 = p100[1], g2 = p100[2];
    const float h0 = p101[0], h1 = p101[1], h2 = p101[2];
    const float j0 = p110[0], j1 = p110[1], j2 = p110[2];
    const float k0 = p111[0], k1 = p111[1], k2 = p111[2];

    const float s0 = a0*c.w000 + b0*c.w001 + c0*c.w010 + e0*c.w011
                   + g0*c.w100 + h0*c.w101 + j0*c.w110 + k0*c.w111;
    const float s1 = a1*c.w000 + b1*c.w001 + c1*c.w010 + e1*c.w011
                   + g1*c.w100 + h1*c.w101 + j1*c.w110 + k1*c.w111;
    const float s2 = a2*c.w000 + b2*c.w001 + c2*c.w010 + e2*c.w011
                   + g2*c.w100 + h2*c.w101 + j2*c.w110 + k2*c.w111;

    const float r0 = f0 + s0, r1 = f1 + s1, r2 = f2 + s2;
    if (OUT_PLANAR) {
        out[tid]            = r0;
        out[NVOX + tid]     = r1;
        out[2 * NVOX + tid] = r2;
    } else {
        float* q = out + 3 * tid;
        q[0] = r0; q[1] = r1; q[2] = r2;
    }
}

extern "C" void kernel_launch(void* const* d_in, const int* in_sizes, int n_in,
                              void* d_out, int out_size, void* d_ws, size_t ws_size,
                              hipStream_t stream) {
    const float* flow = (const float*)d_in[0];
    float* out = (float*)d_out;
    const float inv128 = 1.0f / 128.0f;   // 1 / 2^TIME_STEP (exact power of two)

    float* A;
    float* B;
    const size_t need2 = 2ull * 3 * NVOX * sizeof(float);   // 118 MB
    if (ws_size >= need2) {
        A = (float*)d_ws;
        B = A + 3 * NVOX;
    } else {
        A = (float*)d_ws;   // 59 MB packed buffer
        B = out;            // d_out doubles as packed buffer until step 7
    }

    pack3_kernel<<<NBLK, 256, 0, stream>>>(flow, A, inv128);
    step3_kernel<false><<<NBLK, 256, 0, stream>>>(A, B);    // s1
    step3_kernel<false><<<NBLK, 256, 0, stream>>>(B, A);    // s2
    step3_kernel<false><<<NBLK, 256, 0, stream>>>(A, B);    // s3
    step3_kernel<false><<<NBLK, 256, 0, stream>>>(B, A);    // s4
    step3_kernel<false><<<NBLK, 256, 0, stream>>>(A, B);    // s5
    step3_kernel<false><<<NBLK, 256, 0, stream>>>(B, A);    // s6
    step3_kernel<true ><<<NBLK, 256, 0, stream>>>(A, out);  // s7 -> planar d_out
}